// Round 5
// baseline (118.082 us; speedup 1.0000x reference)
//
#include <hip/hip_runtime.h>
#include <stdint.h>

#define Bd 4
#define Nn 48
#define Mm 48
#define Hh 192
#define Ww 640
#define HW (Hh*Ww)              // 122880 pixels per mask
#define WORDS (HW/64)           // 1920 uint64 words per mask
#define TILE_PX 4096            // one block-iteration; HW % 4096 == 0
#define TILES_A ((Bd*Nn*HW)/TILE_PX)      // 5760
#define TILES_TOTAL (2*TILES_A)           // 11520
#define WSEG 192                // words per pair-tile segment (3 per lane)
#define NWBLK (WORDS/WSEG)      // 10

// ---------------------------------------------------------------------------
// K1: pure pack stream. Persistent grid (2048 blocks = 32 waves/CU exactly),
// grid-stride over 4096-px tiles. Lane owns 16 consecutive px (4x float4,
// 64B chunk — measured equal to fully-coalesced in R2/R3), emits one ushort.
// No LDS, no barriers, no atomics, no reduction: sa/sb moved to K2.
// ---------------------------------------------------------------------------
__global__ void pack_kernel(const float* __restrict__ a, const float* __restrict__ b,
                            ushort* __restrict__ packA, ushort* __restrict__ packB) {
    const int wid = threadIdx.x >> 6, lane = threadIdx.x & 63;
    for (int tile = blockIdx.x; tile < TILES_TOTAL; tile += gridDim.x) {
        const float* src; ushort* dst; int rel;
        if (tile < TILES_A) { src = a; dst = packA; rel = tile; }
        else                { src = b; dst = packB; rel = tile - TILES_A; }
        const long long px = (long long)rel * TILE_PX + wid * 1024 + lane * 16;
        const float4* f = reinterpret_cast<const float4*>(src + px);
        float4 v0 = f[0], v1 = f[1], v2 = f[2], v3 = f[3];
        unsigned int bits =
              (v0.x > 0.0f ? 1u       : 0u) | (v0.y > 0.0f ? 1u << 1  : 0u)
            | (v0.z > 0.0f ? 1u << 2  : 0u) | (v0.w > 0.0f ? 1u << 3  : 0u)
            | (v1.x > 0.0f ? 1u << 4  : 0u) | (v1.y > 0.0f ? 1u << 5  : 0u)
            | (v1.z > 0.0f ? 1u << 6  : 0u) | (v1.w > 0.0f ? 1u << 7  : 0u)
            | (v2.x > 0.0f ? 1u << 8  : 0u) | (v2.y > 0.0f ? 1u << 9  : 0u)
            | (v2.z > 0.0f ? 1u << 10 : 0u) | (v2.w > 0.0f ? 1u << 11 : 0u)
            | (v3.x > 0.0f ? 1u << 12 : 0u) | (v3.y > 0.0f ? 1u << 13 : 0u)
            | (v3.z > 0.0f ? 1u << 14 : 0u) | (v3.w > 0.0f ? 1u << 15 : 0u);
        dst[px >> 4] = (ushort)bits;        // 64 consecutive ushorts per wave
    }
}

__device__ __forceinline__ unsigned int wave_sum(unsigned int s) {
    #pragma unroll
    for (int off = 32; off; off >>= 1) s += __shfl_down(s, off);
    return s;
}

// ---------------------------------------------------------------------------
// K2: tiled pairwise partial intersections + sa/sb partials.
// Block = (b, nblk of 4 n-rows, wblk of 192 words); wave v owns n=nblk*4+v,
// holds its 3 A-words in registers. Loop m: all 4 waves read the SAME 1.5KB
// B segment (L1 hits after first wave), AND+popcount, wave-reduce, one
// atomicAdd per (n,m,wblk). sa from A regs once; sb by wave0 of nblk==0.
// Traffic: 283 MB (old per-pair design) -> ~40 MB.
// ---------------------------------------------------------------------------
__global__ void pair_part_kernel(const uint64_t* __restrict__ packA,
                                 const uint64_t* __restrict__ packB,
                                 unsigned int* __restrict__ interP,
                                 unsigned int* __restrict__ saP,
                                 unsigned int* __restrict__ sbP) {
    const int wblk = blockIdx.x % NWBLK;
    const int nblk = (blockIdx.x / NWBLK) % 12;
    const int bb   = blockIdx.x / (NWBLK * 12);
    const int v = threadIdx.x >> 6, lane = threadIdx.x & 63;
    const int n = nblk * 4 + v;
    const int wbase = wblk * WSEG + lane;               // + k*64, k=0..2

    const uint64_t* Arow = packA + (size_t)(bb * Nn + n) * WORDS + wbase;
    uint64_t a0 = Arow[0], a1 = Arow[64], a2 = Arow[128];

    unsigned int sA = wave_sum((unsigned int)(__popcll(a0) + __popcll(a1) + __popcll(a2)));
    if (lane == 0) atomicAdd(&saP[bb * Nn + n], sA);

    const uint64_t* Bbase = packB + (size_t)bb * Mm * WORDS + wbase;
    for (int m = 0; m < Mm; ++m) {
        const uint64_t* Brow = Bbase + (size_t)m * WORDS;
        uint64_t b0 = Brow[0], b1 = Brow[64], b2 = Brow[128];
        unsigned int s = wave_sum((unsigned int)(__popcll(a0 & b0) + __popcll(a1 & b1) + __popcll(a2 & b2)));
        if (lane == 0) atomicAdd(&interP[(bb * Nn + n) * Mm + m], s);
        if (v == 0 && nblk == 0) {
            unsigned int sB = wave_sum((unsigned int)(__popcll(b0) + __popcll(b1) + __popcll(b2)));
            if (lane == 0) atomicAdd(&sbP[bb * Mm + m], sB);
        }
    }
}

// ---------------------------------------------------------------------------
// K2b: q threshold -> qmask bits. Exact float32 math as the reference
// (all counts are exact integers < 2^24).
// ---------------------------------------------------------------------------
__global__ void q_kernel(const unsigned int* __restrict__ interP,
                         const unsigned int* __restrict__ saP,
                         const unsigned int* __restrict__ sbP,
                         unsigned long long* __restrict__ qmask) {
    int tid = blockIdx.x * blockDim.x + threadIdx.x;
    if (tid >= Bd * Nn * Mm) return;
    int m = tid % Mm, r = tid / Mm;       // r = b*Nn + n
    float inter = (float)interP[tid];
    float un = (float)saP[r] + (float)sbP[(r / Nn) * Mm + m] - inter;
    if (inter / fmaxf(un, 1.0f) > 0.8f)
        atomicOr(&qmask[r], 1ull << m);
}

// ---------------------------------------------------------------------------
// K3+K4 fused: per word, OR of (a_n ^ b_m) over qualifying pairs -> LDS ->
// coalesced float4 expansion to the output.
// ---------------------------------------------------------------------------
__global__ void words_expand_kernel(const uint64_t* __restrict__ packA,
                                    const uint64_t* __restrict__ packB,
                                    const unsigned long long* __restrict__ qmask,
                                    float* __restrict__ out) {
    __shared__ uint64_t sw[256];
    const int t = threadIdx.x;
    const int i = blockIdx.x * 256 + t;       // word index in [0, Bd*WORDS)
    const int bb = i / WORDS, w = i % WORDS;
    uint64_t acc = 0;
    for (int n = 0; n < Nn; ++n) {
        unsigned long long qm = qmask[bb * Nn + n];
        if (!qm) continue;
        uint64_t aw = packA[(size_t)(bb * Nn + n) * WORDS + w];
        while (qm) {
            int m = __ffsll((long long)qm) - 1;
            qm &= qm - 1;
            acc |= aw ^ packB[(size_t)(bb * Mm + m) * WORDS + w];
        }
        if (acc == ~0ull) break;              // word fully covered
    }
    sw[t] = acc;
    __syncthreads();
    float4* out4 = reinterpret_cast<float4*>(out) + (size_t)blockIdx.x * 4096;
    #pragma unroll
    for (int k = 0; k < 16; ++k) {
        int p0 = k * 1024 + 4 * t;
        uint64_t wv = sw[p0 >> 6];
        unsigned int bits = (unsigned int)(wv >> (p0 & 63)) & 0xFu;
        float4 f;
        f.x = (bits & 1u) ? 0.0f : 1.0f;
        f.y = (bits & 2u) ? 0.0f : 1.0f;
        f.z = (bits & 4u) ? 0.0f : 1.0f;
        f.w = (bits & 8u) ? 0.0f : 1.0f;
        out4[k * 256 + t] = f;
    }
}

extern "C" void kernel_launch(void* const* d_in, const int* in_sizes, int n_in,
                              void* d_out, int out_size, void* d_ws, size_t ws_size,
                              hipStream_t stream) {
    const float* a = (const float*)d_in[0];   // stereo_warped_target  [B,N,H,W]
    const float* b = (const float*)d_in[1];   // temporal_warped_target [B,M,H,W]
    float* out = (float*)d_out;               // [B,1,H,W]

    uint8_t* ws = (uint8_t*)d_ws;
    const size_t szPack = (size_t)Bd * Nn * WORDS * sizeof(uint64_t);  // 2.95 MB each
    uint64_t* packA = (uint64_t*)(ws);
    uint64_t* packB = (uint64_t*)(ws + szPack);
    // zero-initialized region: interP | saP | sbP | qmask (contiguous)
    unsigned int* interP = (unsigned int*)(ws + 2 * szPack);           // 9216 u32
    unsigned int* saP = interP + Bd * Nn * Mm;                         // 192 u32
    unsigned int* sbP = saP + Bd * Nn;                                 // 192 u32
    unsigned long long* qmask = (unsigned long long*)(sbP + Bd * Mm);  // 192 u64
    const size_t zeroBytes = (size_t)Bd * Nn * Mm * 4 + (size_t)Bd * (Nn + Mm) * 4
                           + (size_t)Bd * Nn * 8;                      // 39936 B

    hipMemsetAsync(interP, 0, zeroBytes, stream);

    // K1: pure pack stream, persistent grid (2048 blocks = 32 waves/CU)
    pack_kernel<<<2048, 256, 0, stream>>>(a, b, (ushort*)packA, (ushort*)packB);

    // K2: tiled pair partials (480 blocks)
    pair_part_kernel<<<Bd * 12 * NWBLK, 256, 0, stream>>>(packA, packB, interP, saP, sbP);

    // K2b: threshold -> qmask
    q_kernel<<<(Bd * Nn * Mm + 255) / 256, 256, 0, stream>>>(interP, saP, sbP, qmask);

    // K3+K4 fused: zero-words + float expansion
    words_expand_kernel<<<(Bd * WORDS) / 256, 256, 0, stream>>>(packA, packB, qmask, out);
}